// Round 1
// baseline (231.778 us; speedup 1.0000x reference)
//
#include <hip/hip_runtime.h>
#include <math.h>

// Problem constants
//  B=8, C_IN=80, T=1000, D_MODEL=256, D_INNER=512, D_STATE=16, DT_RANK=16,
//  D_CONV=4, N_LABELS=35

// ---- workspace layout (float offsets) ----
#define OFF_W1T   0          // [80][1024]  folded (in_proj@proj) transposed
#define OFF_B1    81920      // [1024]      folded bias
#define OFF_W2S   82944      // [35][512]   (fc_w@out_proj_w) * 1e-3 (mean fold)
#define OFF_AL2   100864     // [512][16]   A = -exp(A_log)
#define OFF_XH    109056     // [8000][512] silu(conv(xh))
#define OFF_SZ    4205056    // [8000][512] silu(z)
#define OFF_DBC   8301056    // [8000][48]  x_proj output (dt|B|C)
#define OFF_PACK  8685056    // [8000][512] float2 (delta, xh)
#define OFF_BC    16877056   // [8000][16]  float2 (B, C)
#define OFF_CHUNK 17133056   // [8cb][8b][512][16] float4 (P,q,S1,S2)
#define OFF_ACCDC 19230208   // [8cb][8b][512] partial sums of xh*sz
#define OFF_YBAR  19262976   // [8][512]
#define WS_FLOATS 19267072   // ~77 MB

__device__ __forceinline__ float silu_f(float v) {
  return v / (1.f + __expf(-v));
}

// ================= prep: folded weights =================
// W1T[c][n] = sum_m in_proj_w[n][m] * proj_w[m][c]   (M=80,N=1024,K=256)
__global__ __launch_bounds__(256) void prep_w1t(const float* __restrict__ proj_w,
                                                const float* __restrict__ in_proj_w,
                                                float* __restrict__ ws) {
  const int nt = blockIdx.x;          // 16 tiles of 64 n
  const int ct = blockIdx.y;          // 5 tiles of 16 c
  const int n0 = nt * 64, c0 = ct * 16;
  __shared__ float Pl[16 * 68];       // [c][k]
  __shared__ float Il[64 * 68];       // [k][n]
  const int tid = threadIdx.x;
  const int ng = tid & 31, cg = tid >> 5;   // 32 n-groups x2, 8 c-groups x2
  float acc[2][2] = {{0.f, 0.f}, {0.f, 0.f}};
  for (int kc = 0; kc < 256; kc += 64) {
    __syncthreads();
    for (int i = tid; i < 16 * 64; i += 256) {
      int k = i >> 4, c = i & 15;
      Pl[c * 68 + k] = proj_w[(kc + k) * 80 + c0 + c];
    }
    for (int i = tid; i < 64 * 64; i += 256) {
      int n = i >> 6, k = i & 63;
      Il[k * 68 + n] = in_proj_w[(n0 + n) * 256 + kc + k];
    }
    __syncthreads();
    for (int k = 0; k < 64; ++k) {
      float p0 = Pl[(cg * 2 + 0) * 68 + k];
      float p1 = Pl[(cg * 2 + 1) * 68 + k];
      float2 iv = *(const float2*)&Il[k * 68 + ng * 2];
      acc[0][0] = fmaf(p0, iv.x, acc[0][0]);
      acc[0][1] = fmaf(p0, iv.y, acc[0][1]);
      acc[1][0] = fmaf(p1, iv.x, acc[1][0]);
      acc[1][1] = fmaf(p1, iv.y, acc[1][1]);
    }
  }
  for (int r = 0; r < 2; ++r)
    for (int q = 0; q < 2; ++q)
      ws[OFF_W1T + (c0 + cg * 2 + r) * 1024 + n0 + ng * 2 + q] = acc[r][q];
}

// b1, W2s (scaled by 1/T), A
__global__ __launch_bounds__(256) void prep_small(const float* __restrict__ proj_b,
                                                  const float* __restrict__ in_proj_w,
                                                  const float* __restrict__ fc_w,
                                                  const float* __restrict__ out_proj_w,
                                                  const float* __restrict__ A_log,
                                                  float* __restrict__ ws) {
  int idx = blockIdx.x * 256 + threadIdx.x;
  if (idx < 1024) {
    float s = 0.f;
    for (int m = 0; m < 256; ++m) s = fmaf(in_proj_w[idx * 256 + m], proj_b[m], s);
    ws[OFF_B1 + idx] = s;
  } else if (idx < 1024 + 17920) {
    int j = idx - 1024;
    int n = j / 512, d = j - n * 512;   // consecutive threads -> consecutive d (coalesced)
    float s = 0.f;
    for (int m = 0; m < 256; ++m) s = fmaf(fc_w[n * 256 + m], out_proj_w[m * 512 + d], s);
    ws[OFF_W2S + j] = s * 1e-3f;        // fold mean over T=1000
  } else if (idx < 1024 + 17920 + 8192) {
    int j = idx - (1024 + 17920);
    ws[OFF_AL2 + j] = -expf(A_log[j]);
  }
}

// ================= K1: xz = X @ W1T + b1, fused conv/silu epilogue =========
// grid (16 n-tiles, 17 t-tiles of 61, 8 b). n-tile<8 -> xh(conv) path, else z path.
__global__ __launch_bounds__(256) void k1_xz(const float* __restrict__ x,
                                             const float* __restrict__ conv_w,
                                             const float* __restrict__ conv_b,
                                             float* __restrict__ ws) {
  const int nt = blockIdx.x;
  const int tt = blockIdx.y;
  const int b  = blockIdx.z;
  const int t0 = tt * 61;
  const int n0 = nt * 64;
  const bool isH = (nt < 8);
  __shared__ float lds[10240];
  float* Xs  = lds;          // [80][64]  X[k][t-row]
  float* Wsh = lds + 5120;   // [80][64]
  const int tid = threadIdx.x;
  for (int i = 0; i < 20; ++i) {
    int idx = tid + 256 * i;             // 5120
    int k = idx >> 6, r = idx & 63;
    int t = t0 - 3 + r;                  // row r <-> global t
    float v = 0.f;
    if (t >= 0 && t < 1000) v = x[(b * 80 + k) * 1000 + t];
    Xs[idx] = v;
    Wsh[idx] = ws[OFF_W1T + k * 1024 + n0 + r];
  }
  __syncthreads();
  const int ng = tid & 15, tg = tid >> 4;   // 16 n-groups x4, 16 t-groups x4
  float acc[4][4];
  {
    float bb[4];
    for (int c = 0; c < 4; ++c) bb[c] = ws[OFF_B1 + n0 + ng * 4 + c];
    for (int r = 0; r < 4; ++r)
      for (int c = 0; c < 4; ++c) acc[r][c] = bb[c];
  }
#pragma unroll 4
  for (int k = 0; k < 80; ++k) {
    float4 xa = *(const float4*)&Xs[k * 64 + tg * 4];
    float4 wv = *(const float4*)&Wsh[k * 64 + ng * 4];
    float xr[4] = {xa.x, xa.y, xa.z, xa.w};
    float wr[4] = {wv.x, wv.y, wv.z, wv.w};
#pragma unroll
    for (int r = 0; r < 4; ++r)
#pragma unroll
      for (int c = 0; c < 4; ++c) acc[r][c] = fmaf(xr[r], wr[c], acc[r][c]);
  }
  __syncthreads();
  if (isH) {
    float* xzl = lds;                     // [64][64]
    for (int r = 0; r < 4; ++r) {
      int row = tg * 4 + r;
      int t = t0 - 3 + row;
      for (int c = 0; c < 4; ++c)
        xzl[row * 64 + ng * 4 + c] = (t >= 0) ? acc[r][c] : 0.f;  // zero-pad pre-conv
    }
    __syncthreads();
    for (int j = tid; j < 61 * 64; j += 256) {
      int i = j >> 6, n = j & 63;
      int t = t0 + i;
      if (t < 1000) {
        int d = n0 + n;
        float w0 = conv_w[d * 4 + 0], w1 = conv_w[d * 4 + 1];
        float w2 = conv_w[d * 4 + 2], w3 = conv_w[d * 4 + 3];
        float v = conv_b[d];
        v = fmaf(w0, xzl[(i + 0) * 64 + n], v);
        v = fmaf(w1, xzl[(i + 1) * 64 + n], v);
        v = fmaf(w2, xzl[(i + 2) * 64 + n], v);
        v = fmaf(w3, xzl[(i + 3) * 64 + n], v);
        ws[OFF_XH + (b * 1000 + t) * 512 + d] = silu_f(v);
      }
    }
  } else {
    int d0 = n0 - 512;
    for (int r = 0; r < 4; ++r) {
      int row = tg * 4 + r;
      int i = row - 3;
      int t = t0 + i;
      if (i >= 0 && t < 1000) {
        float4 o;
        o.x = silu_f(acc[r][0]); o.y = silu_f(acc[r][1]);
        o.z = silu_f(acc[r][2]); o.w = silu_f(acc[r][3]);
        *(float4*)&ws[OFF_SZ + (b * 1000 + t) * 512 + d0 + ng * 4] = o;
      }
    }
  }
}

// ================= K2b: dbc = xh_act @ x_proj_w.T  (M=8000,N=48,K=512) ======
__global__ __launch_bounds__(256) void k2b_dbc(const float* __restrict__ x_proj_w,
                                               float* __restrict__ ws) {
  const int row0 = blockIdx.x * 32;
  __shared__ float Xl[32 * 68];
  __shared__ float Wl[48 * 68];
  const int tid = threadIdx.x;
  const int ng = tid & 15, tg = tid >> 4;   // 16 n-groups x3, 16 t-groups x2
  float acc[2][3] = {{0.f,0.f,0.f},{0.f,0.f,0.f}};
  for (int kc = 0; kc < 512; kc += 64) {
    __syncthreads();
    for (int i = tid; i < 32 * 64; i += 256) {
      int r = i >> 6, c = i & 63;
      Xl[r * 68 + c] = ws[OFF_XH + (row0 + r) * 512 + kc + c];
    }
    for (int i = tid; i < 48 * 64; i += 256) {
      int r = i >> 6, c = i & 63;
      Wl[r * 68 + c] = x_proj_w[r * 512 + kc + c];
    }
    __syncthreads();
    for (int c = 0; c < 64; c += 4) {
      float4 xa0 = *(const float4*)&Xl[(tg * 2 + 0) * 68 + c];
      float4 xa1 = *(const float4*)&Xl[(tg * 2 + 1) * 68 + c];
      float4 w0 = *(const float4*)&Wl[(ng * 3 + 0) * 68 + c];
      float4 w1 = *(const float4*)&Wl[(ng * 3 + 1) * 68 + c];
      float4 w2 = *(const float4*)&Wl[(ng * 3 + 2) * 68 + c];
      acc[0][0] += xa0.x*w0.x + xa0.y*w0.y + xa0.z*w0.z + xa0.w*w0.w;
      acc[0][1] += xa0.x*w1.x + xa0.y*w1.y + xa0.z*w1.z + xa0.w*w1.w;
      acc[0][2] += xa0.x*w2.x + xa0.y*w2.y + xa0.z*w2.z + xa0.w*w2.w;
      acc[1][0] += xa1.x*w0.x + xa1.y*w0.y + xa1.z*w0.z + xa1.w*w0.w;
      acc[1][1] += xa1.x*w1.x + xa1.y*w1.y + xa1.z*w1.z + xa1.w*w1.w;
      acc[1][2] += xa1.x*w2.x + xa1.y*w2.y + xa1.z*w2.z + xa1.w*w2.w;
    }
  }
  for (int r = 0; r < 2; ++r)
    for (int n = 0; n < 3; ++n)
      ws[OFF_DBC + (row0 + tg * 2 + r) * 48 + ng * 3 + n] = acc[r][n];
}

// ================= K2c: delta=softplus(dt@dtw+b); write pack(delta,xh), BC ==
__global__ __launch_bounds__(256) void k2c_pack(const float* __restrict__ dt_proj_w,
                                                const float* __restrict__ dt_proj_b,
                                                float* __restrict__ ws) {
  const int tb = blockIdx.x;   // 125 tiles of 8 t
  const int b  = blockIdx.y;
  const int tid = threadIdx.x;
  __shared__ float dbcl[8 * 48];
  for (int i = tid; i < 8 * 48; i += 256) {
    int tt = i / 48, c = i - tt * 48;
    dbcl[i] = ws[OFF_DBC + (b * 1000 + tb * 8 + tt) * 48 + c];
  }
  __syncthreads();
  if (tid < 128) {
    int tt = tid >> 4, s = tid & 15;
    int row = b * 1000 + tb * 8 + tt;
    *(float2*)&ws[OFF_BC + (row * 16 + s) * 2] =
        make_float2(dbcl[tt * 48 + 16 + s], dbcl[tt * 48 + 32 + s]);
  }
  for (int dd = tid; dd < 512; dd += 256) {
    const float4* wp = (const float4*)(dt_proj_w + dd * 16);
    float4 w0 = wp[0], w1 = wp[1], w2 = wp[2], w3 = wp[3];
    float bias = dt_proj_b[dd];
#pragma unroll
    for (int tt = 0; tt < 8; ++tt) {
      int row = b * 1000 + tb * 8 + tt;
      const float* dr = &dbcl[tt * 48];
      float lin = bias;
      lin = fmaf(dr[0],  w0.x, lin); lin = fmaf(dr[1],  w0.y, lin);
      lin = fmaf(dr[2],  w0.z, lin); lin = fmaf(dr[3],  w0.w, lin);
      lin = fmaf(dr[4],  w1.x, lin); lin = fmaf(dr[5],  w1.y, lin);
      lin = fmaf(dr[6],  w1.z, lin); lin = fmaf(dr[7],  w1.w, lin);
      lin = fmaf(dr[8],  w2.x, lin); lin = fmaf(dr[9],  w2.y, lin);
      lin = fmaf(dr[10], w2.z, lin); lin = fmaf(dr[11], w2.w, lin);
      lin = fmaf(dr[12], w3.x, lin); lin = fmaf(dr[13], w3.y, lin);
      lin = fmaf(dr[14], w3.z, lin); lin = fmaf(dr[15], w3.w, lin);
      float delta = fmaxf(lin, 0.f) + log1pf(__expf(-fabsf(lin)));  // softplus
      float xh = ws[OFF_XH + row * 512 + dd];
      *(float2*)&ws[OFF_PACK + (row * 512 + dd) * 2] = make_float2(delta, xh);
    }
  }
}

// ================= K3: chunked scan pass 1 =================
// lane = (d in 16-group, s); per chunk of 125 t emit (P, q, S1, S2) per (b,d,s)
__global__ __launch_bounds__(256) void k3_scan1(float* __restrict__ ws) {
  const int dg = blockIdx.x;   // 32 groups of 16 d
  const int ck = blockIdx.y;   // 8 chunks
  const int b  = blockIdx.z;
  const int tid = threadIdx.x;
  const int s = tid & 15, dl = tid >> 4;
  const int d = dg * 16 + dl;
  const float a = ws[OFF_AL2 + d * 16 + s];   // A[d][s] (negative)
  const int rowbase = b * 1000 + ck * 125;
  const float2* __restrict__ packp = (const float2*)(ws + OFF_PACK) + rowbase * 512 + d;
  const float*  __restrict__ szp   = ws + OFF_SZ + rowbase * 512 + d;
  const float2* __restrict__ bcp   = (const float2*)(ws + OFF_BC) + rowbase * 16 + s;
  float h = 0.f, cp = 1.f, S1 = 0.f, S2 = 0.f, xacc = 0.f;
#pragma unroll 5
  for (int i = 0; i < 125; ++i) {
    float2 p  = packp[i * 512];   // (delta, xh)
    float sz  = szp[i * 512];
    float2 bc = bcp[i * 16];      // (B, C)
    float e = __expf(p.x * a);    // exp(delta*A)
    cp *= e;
    h = fmaf(e, h, (p.x * p.y) * bc.x);
    float cs = bc.y * sz;
    S1 = fmaf(h, cs, S1);
    S2 = fmaf(cp, cs, S2);
    xacc = fmaf(p.y, sz, xacc);   // sum xh*sz (for D-term; used from s==0)
  }
  int idx = ((ck * 8 + b) * 512 + d) * 16 + s;
  *(float4*)&ws[OFF_CHUNK + idx * 4] = make_float4(cp, h, S1, S2);
  if (s == 0) ws[OFF_ACCDC + (ck * 8 + b) * 512 + d] = xacc;
}

// ================= K4: combine chunks + s-reduce -> ybar =================
__global__ __launch_bounds__(256) void k4_scan2(const float* __restrict__ Dvec,
                                                float* __restrict__ ws) {
  const int dgrp = blockIdx.x;   // 32
  const int b = blockIdx.y;      // 8
  const int tid = threadIdx.x;
  const int s = tid & 15, dl = tid >> 4;
  const int d = dgrp * 16 + dl;
  float h = 0.f, y = 0.f;
#pragma unroll
  for (int k = 0; k < 8; ++k) {
    const float4 f = *(const float4*)&ws[OFF_CHUNK + (((k * 8 + b) * 512 + d) * 16 + s) * 4];
    y = fmaf(f.w, h, y + f.z);   // S1 + S2*h_in
    h = fmaf(f.x, h, f.y);       // P*h_in + q
  }
  y += __shfl_xor(y, 1);
  y += __shfl_xor(y, 2);
  y += __shfl_xor(y, 4);
  y += __shfl_xor(y, 8);
  if (s == 0) {
    float acc = 0.f;
#pragma unroll
    for (int k = 0; k < 8; ++k) acc += ws[OFF_ACCDC + (k * 8 + b) * 512 + d];
    ws[OFF_YBAR + b * 512 + d] = y + Dvec[d] * acc;
  }
}

// ================= K5: out = ybar @ W2s.T + fc_b =================
__global__ __launch_bounds__(64) void k5_out(const float* __restrict__ fc_b,
                                             const float* __restrict__ ws,
                                             float* __restrict__ out) {
  const int b = blockIdx.x;
  const int n = threadIdx.x;
  if (n >= 35) return;
  const float* yb = ws + OFF_YBAR + b * 512;
  const float* w  = ws + OFF_W2S + n * 512;
  float sum = 0.f;
#pragma unroll 8
  for (int k = 0; k < 512; ++k) sum = fmaf(yb[k], w[k], sum);
  out[b * 35 + n] = sum + fc_b[n];
}

extern "C" void kernel_launch(void* const* d_in, const int* in_sizes, int n_in,
                              void* d_out, int out_size, void* d_ws, size_t ws_size,
                              hipStream_t stream) {
  const float* x          = (const float*)d_in[0];
  const float* proj_w     = (const float*)d_in[1];
  const float* proj_b     = (const float*)d_in[2];
  const float* in_proj_w  = (const float*)d_in[3];
  const float* conv_w     = (const float*)d_in[4];
  const float* conv_b     = (const float*)d_in[5];
  const float* x_proj_w   = (const float*)d_in[6];
  const float* dt_proj_w  = (const float*)d_in[7];
  const float* dt_proj_b  = (const float*)d_in[8];
  const float* A_log      = (const float*)d_in[9];
  const float* Dvec       = (const float*)d_in[10];
  const float* out_proj_w = (const float*)d_in[11];
  const float* fc_w       = (const float*)d_in[12];
  const float* fc_b       = (const float*)d_in[13];
  float* ws  = (float*)d_ws;
  float* out = (float*)d_out;
  if (ws_size < (size_t)WS_FLOATS * sizeof(float)) return;  // need ~77 MB scratch

  prep_w1t  <<<dim3(16, 5),    256, 0, stream>>>(proj_w, in_proj_w, ws);
  prep_small<<<106,            256, 0, stream>>>(proj_b, in_proj_w, fc_w, out_proj_w, A_log, ws);
  k1_xz     <<<dim3(16, 17, 8),256, 0, stream>>>(x, conv_w, conv_b, ws);
  k2b_dbc   <<<250,            256, 0, stream>>>(x_proj_w, ws);
  k2c_pack  <<<dim3(125, 8),   256, 0, stream>>>(dt_proj_w, dt_proj_b, ws);
  k3_scan1  <<<dim3(32, 8, 8), 256, 0, stream>>>(ws);
  k4_scan2  <<<dim3(32, 8),    256, 0, stream>>>(Dvec, ws);
  k5_out    <<<8,              64,  0, stream>>>(fc_b, ws, out);
}

// Round 2
// 218.937 us; speedup vs baseline: 1.0586x; 1.0586x over previous
//
#include <hip/hip_runtime.h>
#include <math.h>

// Problem constants
//  B=8, C_IN=80, T=1000, D_MODEL=256, D_INNER=512, D_STATE=16, DT_RANK=16,
//  D_CONV=4, N_LABELS=35

// ---- workspace layout (float offsets) ----
#define OFF_W1T   0          // [80][1024]  folded (in_proj@proj) transposed
#define OFF_B1    81920      // [1024]      folded bias
#define OFF_W2S   82944      // [35][512]   (fc_w@out_proj_w) * 1e-3 (mean fold)
#define OFF_AL2   100864     // [512][16]   A = -exp(A_log)
#define OFF_XH    109056     // [8000][512] silu(conv(xh))
#define OFF_SZ    4205056    // [8000][512] silu(z)
#define OFF_DBC   8301056    // [8000][48]  x_proj output (dt|B|C)
#define OFF_PACK  8685056    // [8000][512] float2 (delta, xh)
#define OFF_BC    16877056   // [8000][16]  float2 (B, C)
#define OFF_CHUNK 17133056   // [8ck][8b][16s][512d] float4 (P,q,S1,S2)
#define OFF_ACCDC 19230208   // [8ck][8b][512] partial sums of xh*sz
#define OFF_YBAR  19262976   // [8][512]
#define WS_FLOATS 19267072   // ~77 MB

__device__ __forceinline__ float silu_f(float v) {
  return v / (1.f + __expf(-v));
}

// ================= prep: folded weights =================
// W1T[c][n] = sum_m in_proj_w[n][m] * proj_w[m][c]   (M=80,N=1024,K=256)
__global__ __launch_bounds__(256) void prep_w1t(const float* __restrict__ proj_w,
                                                const float* __restrict__ in_proj_w,
                                                float* __restrict__ ws) {
  const int nt = blockIdx.x;          // 16 tiles of 64 n
  const int ct = blockIdx.y;          // 5 tiles of 16 c
  const int n0 = nt * 64, c0 = ct * 16;
  __shared__ float Pl[16 * 68];       // [c][k]
  __shared__ float Il[64 * 68];       // [k][n]
  const int tid = threadIdx.x;
  const int ng = tid & 31, cg = tid >> 5;   // 32 n-groups x2, 8 c-groups x2
  float acc[2][2] = {{0.f, 0.f}, {0.f, 0.f}};
  for (int kc = 0; kc < 256; kc += 64) {
    __syncthreads();
    for (int i = tid; i < 16 * 64; i += 256) {
      int k = i >> 4, c = i & 15;
      Pl[c * 68 + k] = proj_w[(kc + k) * 80 + c0 + c];
    }
    for (int i = tid; i < 64 * 64; i += 256) {
      int n = i >> 6, k = i & 63;
      Il[k * 68 + n] = in_proj_w[(n0 + n) * 256 + kc + k];
    }
    __syncthreads();
    for (int k = 0; k < 64; ++k) {
      float p0 = Pl[(cg * 2 + 0) * 68 + k];
      float p1 = Pl[(cg * 2 + 1) * 68 + k];
      float2 iv = *(const float2*)&Il[k * 68 + ng * 2];
      acc[0][0] = fmaf(p0, iv.x, acc[0][0]);
      acc[0][1] = fmaf(p0, iv.y, acc[0][1]);
      acc[1][0] = fmaf(p1, iv.x, acc[1][0]);
      acc[1][1] = fmaf(p1, iv.y, acc[1][1]);
    }
  }
  for (int r = 0; r < 2; ++r)
    for (int q = 0; q < 2; ++q)
      ws[OFF_W1T + (c0 + cg * 2 + r) * 1024 + n0 + ng * 2 + q] = acc[r][q];
}

// b1, W2s (scaled by 1/T), A
__global__ __launch_bounds__(256) void prep_small(const float* __restrict__ proj_b,
                                                  const float* __restrict__ in_proj_w,
                                                  const float* __restrict__ fc_w,
                                                  const float* __restrict__ out_proj_w,
                                                  const float* __restrict__ A_log,
                                                  float* __restrict__ ws) {
  int idx = blockIdx.x * 256 + threadIdx.x;
  if (idx < 1024) {
    float s = 0.f;
    for (int m = 0; m < 256; ++m) s = fmaf(in_proj_w[idx * 256 + m], proj_b[m], s);
    ws[OFF_B1 + idx] = s;
  } else if (idx < 1024 + 17920) {
    int j = idx - 1024;
    int n = j / 512, d = j - n * 512;   // consecutive threads -> consecutive d (coalesced)
    float s = 0.f;
    for (int m = 0; m < 256; ++m) s = fmaf(fc_w[n * 256 + m], out_proj_w[m * 512 + d], s);
    ws[OFF_W2S + j] = s * 1e-3f;        // fold mean over T=1000
  } else if (idx < 1024 + 17920 + 8192) {
    int j = idx - (1024 + 17920);
    ws[OFF_AL2 + j] = -expf(A_log[j]);
  }
}

// ================= K1: xz = X @ W1T + b1, fused conv/silu epilogue =========
// grid (16 n-tiles, 17 t-tiles of 61, 8 b). n-tile<8 -> xh(conv) path, else z path.
__global__ __launch_bounds__(256) void k1_xz(const float* __restrict__ x,
                                             const float* __restrict__ conv_w,
                                             const float* __restrict__ conv_b,
                                             float* __restrict__ ws) {
  const int nt = blockIdx.x;
  const int tt = blockIdx.y;
  const int b  = blockIdx.z;
  const int t0 = tt * 61;
  const int n0 = nt * 64;
  const bool isH = (nt < 8);
  __shared__ float lds[10240];
  float* Xs  = lds;          // [80][64]  X[k][t-row]
  float* Wsh = lds + 5120;   // [80][64]
  const int tid = threadIdx.x;
  for (int i = 0; i < 20; ++i) {
    int idx = tid + 256 * i;             // 5120
    int k = idx >> 6, r = idx & 63;
    int t = t0 - 3 + r;                  // row r <-> global t
    float v = 0.f;
    if (t >= 0 && t < 1000) v = x[(b * 80 + k) * 1000 + t];
    Xs[idx] = v;
    Wsh[idx] = ws[OFF_W1T + k * 1024 + n0 + r];
  }
  __syncthreads();
  const int ng = tid & 15, tg = tid >> 4;   // 16 n-groups x4, 16 t-groups x4
  float acc[4][4];
  {
    float bb[4];
    for (int c = 0; c < 4; ++c) bb[c] = ws[OFF_B1 + n0 + ng * 4 + c];
    for (int r = 0; r < 4; ++r)
      for (int c = 0; c < 4; ++c) acc[r][c] = bb[c];
  }
#pragma unroll 4
  for (int k = 0; k < 80; ++k) {
    float4 xa = *(const float4*)&Xs[k * 64 + tg * 4];
    float4 wv = *(const float4*)&Wsh[k * 64 + ng * 4];
    float xr[4] = {xa.x, xa.y, xa.z, xa.w};
    float wr[4] = {wv.x, wv.y, wv.z, wv.w};
#pragma unroll
    for (int r = 0; r < 4; ++r)
#pragma unroll
      for (int c = 0; c < 4; ++c) acc[r][c] = fmaf(xr[r], wr[c], acc[r][c]);
  }
  __syncthreads();
  if (isH) {
    float* xzl = lds;                     // [64][64]
    for (int r = 0; r < 4; ++r) {
      int row = tg * 4 + r;
      int t = t0 - 3 + row;
      for (int c = 0; c < 4; ++c)
        xzl[row * 64 + ng * 4 + c] = (t >= 0) ? acc[r][c] : 0.f;  // zero-pad pre-conv
    }
    __syncthreads();
    for (int j = tid; j < 61 * 64; j += 256) {
      int i = j >> 6, n = j & 63;
      int t = t0 + i;
      if (t < 1000) {
        int d = n0 + n;
        float w0 = conv_w[d * 4 + 0], w1 = conv_w[d * 4 + 1];
        float w2 = conv_w[d * 4 + 2], w3 = conv_w[d * 4 + 3];
        float v = conv_b[d];
        v = fmaf(w0, xzl[(i + 0) * 64 + n], v);
        v = fmaf(w1, xzl[(i + 1) * 64 + n], v);
        v = fmaf(w2, xzl[(i + 2) * 64 + n], v);
        v = fmaf(w3, xzl[(i + 3) * 64 + n], v);
        ws[OFF_XH + (b * 1000 + t) * 512 + d] = silu_f(v);
      }
    }
  } else {
    int d0 = n0 - 512;
    for (int r = 0; r < 4; ++r) {
      int row = tg * 4 + r;
      int i = row - 3;
      int t = t0 + i;
      if (i >= 0 && t < 1000) {
        float4 o;
        o.x = silu_f(acc[r][0]); o.y = silu_f(acc[r][1]);
        o.z = silu_f(acc[r][2]); o.w = silu_f(acc[r][3]);
        *(float4*)&ws[OFF_SZ + (b * 1000 + t) * 512 + d0 + ng * 4] = o;
      }
    }
  }
}

// ================= K2b: dbc = xh_act @ x_proj_w.T  (M=8000,N=48,K=512) ======
__global__ __launch_bounds__(256) void k2b_dbc(const float* __restrict__ x_proj_w,
                                               float* __restrict__ ws) {
  const int row0 = blockIdx.x * 32;
  __shared__ float Xl[32 * 68];
  __shared__ float Wl[48 * 68];
  const int tid = threadIdx.x;
  const int ng = tid & 15, tg = tid >> 4;   // 16 n-groups x3, 16 t-groups x2
  float acc[2][3] = {{0.f,0.f,0.f},{0.f,0.f,0.f}};
  for (int kc = 0; kc < 512; kc += 64) {
    __syncthreads();
    for (int i = tid; i < 32 * 64; i += 256) {
      int r = i >> 6, c = i & 63;
      Xl[r * 68 + c] = ws[OFF_XH + (row0 + r) * 512 + kc + c];
    }
    for (int i = tid; i < 48 * 64; i += 256) {
      int r = i >> 6, c = i & 63;
      Wl[r * 68 + c] = x_proj_w[r * 512 + kc + c];
    }
    __syncthreads();
    for (int c = 0; c < 64; c += 4) {
      float4 xa0 = *(const float4*)&Xl[(tg * 2 + 0) * 68 + c];
      float4 xa1 = *(const float4*)&Xl[(tg * 2 + 1) * 68 + c];
      float4 w0 = *(const float4*)&Wl[(ng * 3 + 0) * 68 + c];
      float4 w1 = *(const float4*)&Wl[(ng * 3 + 1) * 68 + c];
      float4 w2 = *(const float4*)&Wl[(ng * 3 + 2) * 68 + c];
      acc[0][0] += xa0.x*w0.x + xa0.y*w0.y + xa0.z*w0.z + xa0.w*w0.w;
      acc[0][1] += xa0.x*w1.x + xa0.y*w1.y + xa0.z*w1.z + xa0.w*w1.w;
      acc[0][2] += xa0.x*w2.x + xa0.y*w2.y + xa0.z*w2.z + xa0.w*w2.w;
      acc[1][0] += xa1.x*w0.x + xa1.y*w0.y + xa1.z*w0.z + xa1.w*w0.w;
      acc[1][1] += xa1.x*w1.x + xa1.y*w1.y + xa1.z*w1.z + xa1.w*w1.w;
      acc[1][2] += xa1.x*w2.x + xa1.y*w2.y + xa1.z*w2.z + xa1.w*w2.w;
    }
  }
  for (int r = 0; r < 2; ++r)
    for (int n = 0; n < 3; ++n)
      ws[OFF_DBC + (row0 + tg * 2 + r) * 48 + ng * 3 + n] = acc[r][n];
}

// ================= K2c: delta=softplus(dt@dtw+b); write pack(delta,xh), BC ==
__global__ __launch_bounds__(256) void k2c_pack(const float* __restrict__ dt_proj_w,
                                                const float* __restrict__ dt_proj_b,
                                                float* __restrict__ ws) {
  const int tb = blockIdx.x;   // 125 tiles of 8 t
  const int b  = blockIdx.y;
  const int tid = threadIdx.x;
  __shared__ float dbcl[8 * 48];
  for (int i = tid; i < 8 * 48; i += 256) {
    int tt = i / 48, c = i - tt * 48;
    dbcl[i] = ws[OFF_DBC + (b * 1000 + tb * 8 + tt) * 48 + c];
  }
  __syncthreads();
  if (tid < 128) {
    int tt = tid >> 4, s = tid & 15;
    int row = b * 1000 + tb * 8 + tt;
    *(float2*)&ws[OFF_BC + (row * 16 + s) * 2] =
        make_float2(dbcl[tt * 48 + 16 + s], dbcl[tt * 48 + 32 + s]);
  }
  for (int dd = tid; dd < 512; dd += 256) {
    const float4* wp = (const float4*)(dt_proj_w + dd * 16);
    float4 w0 = wp[0], w1 = wp[1], w2 = wp[2], w3 = wp[3];
    float bias = dt_proj_b[dd];
#pragma unroll
    for (int tt = 0; tt < 8; ++tt) {
      int row = b * 1000 + tb * 8 + tt;
      const float* dr = &dbcl[tt * 48];
      float lin = bias;
      lin = fmaf(dr[0],  w0.x, lin); lin = fmaf(dr[1],  w0.y, lin);
      lin = fmaf(dr[2],  w0.z, lin); lin = fmaf(dr[3],  w0.w, lin);
      lin = fmaf(dr[4],  w1.x, lin); lin = fmaf(dr[5],  w1.y, lin);
      lin = fmaf(dr[6],  w1.z, lin); lin = fmaf(dr[7],  w1.w, lin);
      lin = fmaf(dr[8],  w2.x, lin); lin = fmaf(dr[9],  w2.y, lin);
      lin = fmaf(dr[10], w2.z, lin); lin = fmaf(dr[11], w2.w, lin);
      lin = fmaf(dr[12], w3.x, lin); lin = fmaf(dr[13], w3.y, lin);
      lin = fmaf(dr[14], w3.z, lin); lin = fmaf(dr[15], w3.w, lin);
      float delta = fmaxf(lin, 0.f) + log1pf(__expf(-fabsf(lin)));  // softplus
      float xh = ws[OFF_XH + row * 512 + dd];
      *(float2*)&ws[OFF_PACK + (row * 512 + dd) * 2] = make_float2(delta, xh);
    }
  }
}

// ================= K3: chunked scan pass 1 (d-major lanes) =================
// block 256 = 64 d-lanes x 4 waves; each thread carries 4 s-chains.
// Per-wave loads: 64 consecutive float2 (512B) pack, 256B sz, BC wave-uniform.
__global__ __launch_bounds__(256) void k3_scan1(float* __restrict__ ws) {
  const int dg = blockIdx.x;   // 8 groups of 64 d
  const int ck = blockIdx.y;   // 8 chunks of 125 t
  const int b  = blockIdx.z;
  const int tid = threadIdx.x;
  const int lane = tid & 63;        // d within group
  const int sq = tid >> 6;          // 0..3; s = sq*4 + j
  const int d = dg * 64 + lane;
  float a[4];
#pragma unroll
  for (int j = 0; j < 4; ++j) a[j] = ws[OFF_AL2 + d * 16 + sq * 4 + j];
  const int rowbase = b * 1000 + ck * 125;
  const float2* __restrict__ packp = (const float2*)(ws + OFF_PACK) + rowbase * 512 + d;
  const float*  __restrict__ szp   = ws + OFF_SZ + rowbase * 512 + d;
  const float2* __restrict__ bcp   = (const float2*)(ws + OFF_BC) + rowbase * 16 + sq * 4;
  float h[4]  = {0.f, 0.f, 0.f, 0.f};
  float cp[4] = {1.f, 1.f, 1.f, 1.f};
  float S1[4] = {0.f, 0.f, 0.f, 0.f};
  float S2[4] = {0.f, 0.f, 0.f, 0.f};
  float xacc = 0.f;
#pragma unroll 5
  for (int i = 0; i < 125; ++i) {
    float2 p  = packp[i * 512];   // (delta, xh) — coalesced
    float sz  = szp[i * 512];     // coalesced
    float du = p.x * p.y;
    xacc = fmaf(p.y, sz, xacc);
#pragma unroll
    for (int j = 0; j < 4; ++j) {
      float2 bc = bcp[i * 16 + j];   // wave-uniform broadcast
      float e = __expf(p.x * a[j]);
      cp[j] *= e;
      h[j] = fmaf(e, h[j], du * bc.x);
      float cs = bc.y * sz;
      S1[j] = fmaf(h[j], cs, S1[j]);
      S2[j] = fmaf(cp[j], cs, S2[j]);
    }
  }
#pragma unroll
  for (int j = 0; j < 4; ++j) {
    int s = sq * 4 + j;
    int idx = ((ck * 8 + b) * 16 + s) * 512 + d;   // [ck][b][s][d] — coalesced store
    *(float4*)&ws[OFF_CHUNK + idx * 4] = make_float4(cp[j], h[j], S1[j], S2[j]);
  }
  if (sq == 0) ws[OFF_ACCDC + (ck * 8 + b) * 512 + d] = xacc;
}

// ================= K4: combine chunks + s-reduce -> ybar =================
// block 256 = 64 d-lanes x 4 waves (4 s each); LDS reduce over waves.
__global__ __launch_bounds__(256) void k4_scan2(const float* __restrict__ Dvec,
                                                float* __restrict__ ws) {
  const int dg = blockIdx.x;   // 8 groups of 64 d
  const int b  = blockIdx.y;
  const int tid = threadIdx.x;
  const int lane = tid & 63, sq = tid >> 6;
  const int d = dg * 64 + lane;
  float h[4] = {0.f, 0.f, 0.f, 0.f};
  float y = 0.f;
#pragma unroll
  for (int k = 0; k < 8; ++k) {
#pragma unroll
    for (int j = 0; j < 4; ++j) {
      int s = sq * 4 + j;
      const float4 f = *(const float4*)&ws[OFF_CHUNK + (((k * 8 + b) * 16 + s) * 512 + d) * 4];
      y = fmaf(f.w, h[j], y + f.z);   // S1 + S2*h_in
      h[j] = fmaf(f.x, h[j], f.y);    // P*h_in + q
    }
  }
  __shared__ float ys[4][64];
  ys[sq][lane] = y;
  __syncthreads();
  if (sq == 0) {
    float yt = ys[0][lane] + ys[1][lane] + ys[2][lane] + ys[3][lane];
    float acc = 0.f;
#pragma unroll
    for (int k = 0; k < 8; ++k) acc += ws[OFF_ACCDC + (k * 8 + b) * 512 + d];
    ws[OFF_YBAR + b * 512 + d] = yt + Dvec[d] * acc;
  }
}

// ================= K5: out = ybar @ W2s.T + fc_b =================
__global__ __launch_bounds__(64) void k5_out(const float* __restrict__ fc_b,
                                             const float* __restrict__ ws,
                                             float* __restrict__ out) {
  const int b = blockIdx.x;
  const int n = threadIdx.x;
  if (n >= 35) return;
  const float* yb = ws + OFF_YBAR + b * 512;
  const float* w  = ws + OFF_W2S + n * 512;
  float sum = 0.f;
#pragma unroll 8
  for (int k = 0; k < 512; ++k) sum = fmaf(yb[k], w[k], sum);
  out[b * 35 + n] = sum + fc_b[n];
}

extern "C" void kernel_launch(void* const* d_in, const int* in_sizes, int n_in,
                              void* d_out, int out_size, void* d_ws, size_t ws_size,
                              hipStream_t stream) {
  const float* x          = (const float*)d_in[0];
  const float* proj_w     = (const float*)d_in[1];
  const float* proj_b     = (const float*)d_in[2];
  const float* in_proj_w  = (const float*)d_in[3];
  const float* conv_w     = (const float*)d_in[4];
  const float* conv_b     = (const float*)d_in[5];
  const float* x_proj_w   = (const float*)d_in[6];
  const float* dt_proj_w  = (const float*)d_in[7];
  const float* dt_proj_b  = (const float*)d_in[8];
  const float* A_log      = (const float*)d_in[9];
  const float* Dvec       = (const float*)d_in[10];
  const float* out_proj_w = (const float*)d_in[11];
  const float* fc_w       = (const float*)d_in[12];
  const float* fc_b       = (const float*)d_in[13];
  float* ws  = (float*)d_ws;
  float* out = (float*)d_out;
  if (ws_size < (size_t)WS_FLOATS * sizeof(float)) return;  // need ~77 MB scratch

  prep_w1t  <<<dim3(16, 5),    256, 0, stream>>>(proj_w, in_proj_w, ws);
  prep_small<<<106,            256, 0, stream>>>(proj_b, in_proj_w, fc_w, out_proj_w, A_log, ws);
  k1_xz     <<<dim3(16, 17, 8),256, 0, stream>>>(x, conv_w, conv_b, ws);
  k2b_dbc   <<<250,            256, 0, stream>>>(x_proj_w, ws);
  k2c_pack  <<<dim3(125, 8),   256, 0, stream>>>(dt_proj_w, dt_proj_b, ws);
  k3_scan1  <<<dim3(8, 8, 8),  256, 0, stream>>>(ws);
  k4_scan2  <<<dim3(8, 8),     256, 0, stream>>>(Dvec, ws);
  k5_out    <<<8,              64,  0, stream>>>(fc_b, ws, out);
}

// Round 3
// 171.964 us; speedup vs baseline: 1.3478x; 1.2732x over previous
//
#include <hip/hip_runtime.h>
#include <math.h>

// Problem constants
//  B=8, C_IN=80, T=1000, D_MODEL=256, D_INNER=512, D_STATE=16, DT_RANK=16,
//  D_CONV=4, N_LABELS=35

// ---- workspace layout (float offsets) ----
#define OFF_W1T   0          // [80][1024]  folded (in_proj@proj) transposed
#define OFF_B1    81920      // [1024]      folded bias
#define OFF_W2S   82944      // [35][512]   (fc_w@out_proj_w) * 1e-3 (mean fold)
#define OFF_AL2   100864     // [512][16]   A = -exp(A_log)
#define OFF_XH    109056     // [8000][512] silu(conv(xh))
#define OFF_SZ    4205056    // [8000][512] silu(z)
#define OFF_PACK  8301056    // [8000][512] float2 (delta, xh)
#define OFF_BC    16493056   // [8000][16]  float2 (B, C)
#define OFF_CHUNK 16749056   // [8ck][8b][16s][512d] float4 (P,q,S1,S2)
#define OFF_DBCP  OFF_CHUNK  // [2ks][8000][48] k2b partials — dead before CHUNK written
#define OFF_ACCDC 18846208   // [8ck][8b][512] partial sums of xh*sz
#define OFF_YBAR  18878976   // [8][512]
#define WS_FLOATS 18883072   // ~75.5 MB

__device__ __forceinline__ float silu_f(float v) {
  return v / (1.f + __expf(-v));
}

// ================= prep: folded weights =================
// W1T[c][n] = sum_m in_proj_w[n][m] * proj_w[m][c]   (M=80,N=1024,K=256)
__global__ __launch_bounds__(256) void prep_w1t(const float* __restrict__ proj_w,
                                                const float* __restrict__ in_proj_w,
                                                float* __restrict__ ws) {
  const int nt = blockIdx.x;          // 16 tiles of 64 n
  const int ct = blockIdx.y;          // 5 tiles of 16 c
  const int n0 = nt * 64, c0 = ct * 16;
  __shared__ float Pl[16 * 68];       // [c][k]
  __shared__ float Il[64 * 68];       // [k][n]
  const int tid = threadIdx.x;
  const int ng = tid & 31, cg = tid >> 5;   // 32 n-groups x2, 8 c-groups x2
  float acc[2][2] = {{0.f, 0.f}, {0.f, 0.f}};
  for (int kc = 0; kc < 256; kc += 64) {
    __syncthreads();
    for (int i = tid; i < 16 * 64; i += 256) {
      int k = i >> 4, c = i & 15;
      Pl[c * 68 + k] = proj_w[(kc + k) * 80 + c0 + c];
    }
    for (int i = tid; i < 64 * 64; i += 256) {
      int n = i >> 6, k = i & 63;
      Il[k * 68 + n] = in_proj_w[(n0 + n) * 256 + kc + k];
    }
    __syncthreads();
    for (int k = 0; k < 64; ++k) {
      float p0 = Pl[(cg * 2 + 0) * 68 + k];
      float p1 = Pl[(cg * 2 + 1) * 68 + k];
      float2 iv = *(const float2*)&Il[k * 68 + ng * 2];
      acc[0][0] = fmaf(p0, iv.x, acc[0][0]);
      acc[0][1] = fmaf(p0, iv.y, acc[0][1]);
      acc[1][0] = fmaf(p1, iv.x, acc[1][0]);
      acc[1][1] = fmaf(p1, iv.y, acc[1][1]);
    }
  }
  for (int r = 0; r < 2; ++r)
    for (int q = 0; q < 2; ++q)
      ws[OFF_W1T + (c0 + cg * 2 + r) * 1024 + n0 + ng * 2 + q] = acc[r][q];
}

// b1, W2s (scaled by 1/T), A
__global__ __launch_bounds__(256) void prep_small(const float* __restrict__ proj_b,
                                                  const float* __restrict__ in_proj_w,
                                                  const float* __restrict__ fc_w,
                                                  const float* __restrict__ out_proj_w,
                                                  const float* __restrict__ A_log,
                                                  float* __restrict__ ws) {
  int idx = blockIdx.x * 256 + threadIdx.x;
  if (idx < 1024) {
    float s = 0.f;
    for (int m = 0; m < 256; ++m) s = fmaf(in_proj_w[idx * 256 + m], proj_b[m], s);
    ws[OFF_B1 + idx] = s;
  } else if (idx < 1024 + 17920) {
    int j = idx - 1024;
    int n = j / 512, d = j - n * 512;   // consecutive threads -> consecutive d (coalesced)
    float s = 0.f;
    for (int m = 0; m < 256; ++m) s = fmaf(fc_w[n * 256 + m], out_proj_w[m * 512 + d], s);
    ws[OFF_W2S + j] = s * 1e-3f;        // fold mean over T=1000
  } else if (idx < 1024 + 17920 + 8192) {
    int j = idx - (1024 + 17920);
    ws[OFF_AL2 + j] = -expf(A_log[j]);
  }
}

// ================= K1: xz = X @ W1T + b1, fused conv/silu epilogue =========
// grid (16 n-tiles, 17 t-tiles of 61, 8 b). n-tile<8 -> xh(conv) path, else z path.
__global__ __launch_bounds__(256) void k1_xz(const float* __restrict__ x,
                                             const float* __restrict__ conv_w,
                                             const float* __restrict__ conv_b,
                                             float* __restrict__ ws) {
  const int nt = blockIdx.x;
  const int tt = blockIdx.y;
  const int b  = blockIdx.z;
  const int t0 = tt * 61;
  const int n0 = nt * 64;
  const bool isH = (nt < 8);
  __shared__ float lds[10240];
  float* Xs  = lds;          // [80][64]  X[k][t-row]
  float* Wsh = lds + 5120;   // [80][64]
  const int tid = threadIdx.x;
  for (int i = 0; i < 20; ++i) {
    int idx = tid + 256 * i;             // 5120
    int k = idx >> 6, r = idx & 63;
    int t = t0 - 3 + r;                  // row r <-> global t
    float v = 0.f;
    if (t >= 0 && t < 1000) v = x[(b * 80 + k) * 1000 + t];
    Xs[idx] = v;
    Wsh[idx] = ws[OFF_W1T + k * 1024 + n0 + r];
  }
  __syncthreads();
  const int ng = tid & 15, tg = tid >> 4;   // 16 n-groups x4, 16 t-groups x4
  float acc[4][4];
  {
    float bb[4];
    for (int c = 0; c < 4; ++c) bb[c] = ws[OFF_B1 + n0 + ng * 4 + c];
    for (int r = 0; r < 4; ++r)
      for (int c = 0; c < 4; ++c) acc[r][c] = bb[c];
  }
#pragma unroll 4
  for (int k = 0; k < 80; ++k) {
    float4 xa = *(const float4*)&Xs[k * 64 + tg * 4];
    float4 wv = *(const float4*)&Wsh[k * 64 + ng * 4];
    float xr[4] = {xa.x, xa.y, xa.z, xa.w};
    float wr[4] = {wv.x, wv.y, wv.z, wv.w};
#pragma unroll
    for (int r = 0; r < 4; ++r)
#pragma unroll
      for (int c = 0; c < 4; ++c) acc[r][c] = fmaf(xr[r], wr[c], acc[r][c]);
  }
  __syncthreads();
  if (isH) {
    float* xzl = lds;                     // [64][64]
    for (int r = 0; r < 4; ++r) {
      int row = tg * 4 + r;
      int t = t0 - 3 + row;
      for (int c = 0; c < 4; ++c)
        xzl[row * 64 + ng * 4 + c] = (t >= 0) ? acc[r][c] : 0.f;  // zero-pad pre-conv
    }
    __syncthreads();
    for (int j = tid; j < 61 * 64; j += 256) {
      int i = j >> 6, n = j & 63;
      int t = t0 + i;
      if (t < 1000) {
        int d = n0 + n;
        float w0 = conv_w[d * 4 + 0], w1 = conv_w[d * 4 + 1];
        float w2 = conv_w[d * 4 + 2], w3 = conv_w[d * 4 + 3];
        float v = conv_b[d];
        v = fmaf(w0, xzl[(i + 0) * 64 + n], v);
        v = fmaf(w1, xzl[(i + 1) * 64 + n], v);
        v = fmaf(w2, xzl[(i + 2) * 64 + n], v);
        v = fmaf(w3, xzl[(i + 3) * 64 + n], v);
        ws[OFF_XH + (b * 1000 + t) * 512 + d] = silu_f(v);
      }
    }
  } else {
    int d0 = n0 - 512;
    for (int r = 0; r < 4; ++r) {
      int row = tg * 4 + r;
      int i = row - 3;
      int t = t0 + i;
      if (i >= 0 && t < 1000) {
        float4 o;
        o.x = silu_f(acc[r][0]); o.y = silu_f(acc[r][1]);
        o.z = silu_f(acc[r][2]); o.w = silu_f(acc[r][3]);
        *(float4*)&ws[OFF_SZ + (b * 1000 + t) * 512 + d0 + ng * 4] = o;
      }
    }
  }
}

// ================= K2b: dbc partials = xh @ x_proj_w.T (split-K x2) =========
// grid (500 row-tiles of 16, 2 K-halves). 1000 blocks.
__global__ __launch_bounds__(256) void k2b_dbc(const float* __restrict__ x_proj_w,
                                               float* __restrict__ ws) {
  const int row0 = blockIdx.x * 16;
  const int ks   = blockIdx.y;          // K half
  const int k0   = ks * 256;
  __shared__ float Xl[16 * 68];
  __shared__ float Wl[48 * 68];
  const int tid = threadIdx.x;
  const int ng = tid & 15, rg = tid >> 4;   // 16 n-groups x3, 16 rows x1
  float acc[3] = {0.f, 0.f, 0.f};
  for (int kc = 0; kc < 256; kc += 64) {
    __syncthreads();
    for (int i = tid; i < 16 * 64; i += 256) {
      int r = i >> 6, c = i & 63;
      Xl[r * 68 + c] = ws[OFF_XH + (row0 + r) * 512 + k0 + kc + c];
    }
    for (int i = tid; i < 48 * 64; i += 256) {
      int r = i >> 6, c = i & 63;
      Wl[r * 68 + c] = x_proj_w[r * 512 + k0 + kc + c];
    }
    __syncthreads();
    for (int c = 0; c < 64; c += 4) {
      float4 xa = *(const float4*)&Xl[rg * 68 + c];
      float4 w0 = *(const float4*)&Wl[(ng * 3 + 0) * 68 + c];
      float4 w1 = *(const float4*)&Wl[(ng * 3 + 1) * 68 + c];
      float4 w2 = *(const float4*)&Wl[(ng * 3 + 2) * 68 + c];
      acc[0] += xa.x*w0.x + xa.y*w0.y + xa.z*w0.z + xa.w*w0.w;
      acc[1] += xa.x*w1.x + xa.y*w1.y + xa.z*w1.z + xa.w*w1.w;
      acc[2] += xa.x*w2.x + xa.y*w2.y + xa.z*w2.z + xa.w*w2.w;
    }
  }
  for (int n = 0; n < 3; ++n)
    ws[OFF_DBCP + ks * 384000 + (row0 + rg) * 48 + ng * 3 + n] = acc[n];
}

// ================= K2c: delta=softplus(dt@dtw+b); write pack(delta,xh), BC ==
__global__ __launch_bounds__(256) void k2c_pack(const float* __restrict__ dt_proj_w,
                                                const float* __restrict__ dt_proj_b,
                                                float* __restrict__ ws) {
  const int tb = blockIdx.x;   // 125 tiles of 8 t
  const int b  = blockIdx.y;
  const int tid = threadIdx.x;
  __shared__ float dbcl[8 * 48];
  for (int i = tid; i < 8 * 48; i += 256) {
    int tt = i / 48, c = i - tt * 48;
    int row = b * 1000 + tb * 8 + tt;
    dbcl[i] = ws[OFF_DBCP + row * 48 + c] + ws[OFF_DBCP + 384000 + row * 48 + c];
  }
  __syncthreads();
  if (tid < 128) {
    int tt = tid >> 4, s = tid & 15;
    int row = b * 1000 + tb * 8 + tt;
    *(float2*)&ws[OFF_BC + (row * 16 + s) * 2] =
        make_float2(dbcl[tt * 48 + 16 + s], dbcl[tt * 48 + 32 + s]);
  }
  for (int dd = tid; dd < 512; dd += 256) {
    const float4* wp = (const float4*)(dt_proj_w + dd * 16);
    float4 w0 = wp[0], w1 = wp[1], w2 = wp[2], w3 = wp[3];
    float bias = dt_proj_b[dd];
#pragma unroll
    for (int tt = 0; tt < 8; ++tt) {
      int row = b * 1000 + tb * 8 + tt;
      const float* dr = &dbcl[tt * 48];
      float lin = bias;
      lin = fmaf(dr[0],  w0.x, lin); lin = fmaf(dr[1],  w0.y, lin);
      lin = fmaf(dr[2],  w0.z, lin); lin = fmaf(dr[3],  w0.w, lin);
      lin = fmaf(dr[4],  w1.x, lin); lin = fmaf(dr[5],  w1.y, lin);
      lin = fmaf(dr[6],  w1.z, lin); lin = fmaf(dr[7],  w1.w, lin);
      lin = fmaf(dr[8],  w2.x, lin); lin = fmaf(dr[9],  w2.y, lin);
      lin = fmaf(dr[10], w2.z, lin); lin = fmaf(dr[11], w2.w, lin);
      lin = fmaf(dr[12], w3.x, lin); lin = fmaf(dr[13], w3.y, lin);
      lin = fmaf(dr[14], w3.z, lin); lin = fmaf(dr[15], w3.w, lin);
      float delta = fmaxf(lin, 0.f) + log1pf(__expf(-fabsf(lin)));  // softplus
      float xh = ws[OFF_XH + row * 512 + dd];
      *(float2*)&ws[OFF_PACK + (row * 512 + dd) * 2] = make_float2(delta, xh);
    }
  }
}

// ================= K3: chunked scan pass 1 (d-major, 8 waves, pipelined) ====
// block 512 = 64 d-lanes x 8 waves; each thread carries 2 s-chains.
// BC staged in LDS; pack/sz loads in 5-wide double-buffered groups.
#define K3_LOADG(P, Z, g)                                   \
  {                                                         \
    const int _b = (g) * 5;                                 \
    _Pragma("unroll") for (int _u = 0; _u < 5; ++_u) {      \
      P[_u] = packp[(_b + _u) * 512];                       \
      Z[_u] = szp[(_b + _u) * 512];                         \
    }                                                       \
  }
#define K3_COMPG(P, Z, g)                                                   \
  {                                                                         \
    const int _b = (g) * 5;                                                 \
    _Pragma("unroll") for (int _u = 0; _u < 5; ++_u) {                      \
      float2 p = P[_u];                                                     \
      float sz = Z[_u];                                                     \
      float du = p.x * p.y;                                                 \
      xacc = fmaf(p.y, sz, xacc);                                           \
      float4 bc = *(const float4*)&bcl[(_b + _u) * 32 + wv * 4];            \
      float e0 = __expf(p.x * a0), e1 = __expf(p.x * a1);                   \
      cp0 *= e0; cp1 *= e1;                                                 \
      h0 = fmaf(e0, h0, du * bc.x);                                         \
      h1 = fmaf(e1, h1, du * bc.z);                                         \
      float cs0 = bc.y * sz, cs1 = bc.w * sz;                               \
      S10 = fmaf(h0, cs0, S10); S11 = fmaf(h1, cs1, S11);                   \
      S20 = fmaf(cp0, cs0, S20); S21 = fmaf(cp1, cs1, S21);                 \
    }                                                                       \
  }

__global__ __launch_bounds__(512) void k3_scan1(float* __restrict__ ws) {
  const int dg = blockIdx.x;   // 8 groups of 64 d
  const int ck = blockIdx.y;   // 8 chunks of 125 t
  const int b  = blockIdx.z;
  const int tid = threadIdx.x;
  const int lane = tid & 63;        // d within group
  const int wv = tid >> 6;          // 0..7; s = wv*2 + {0,1}
  const int d = dg * 64 + lane;
  const float2 av = *(const float2*)&ws[OFF_AL2 + d * 16 + wv * 2];
  const float a0 = av.x, a1 = av.y;
  const int rowbase = b * 1000 + ck * 125;
  __shared__ __align__(16) float bcl[4000];   // [125 t][16 s][2]
  for (int i = tid; i < 4000; i += 512) bcl[i] = ws[OFF_BC + rowbase * 32 + i];
  __syncthreads();
  const float2* __restrict__ packp = (const float2*)(ws + OFF_PACK) + rowbase * 512 + d;
  const float*  __restrict__ szp   = ws + OFF_SZ + rowbase * 512 + d;
  float h0 = 0.f, h1 = 0.f, cp0 = 1.f, cp1 = 1.f;
  float S10 = 0.f, S11 = 0.f, S20 = 0.f, S21 = 0.f, xacc = 0.f;
  float2 PA[5], PB[5];
  float  ZA[5], ZB[5];
  K3_LOADG(PA, ZA, 0);
  for (int g = 0; g < 12; ++g) {
    K3_LOADG(PB, ZB, 2 * g + 1);
    K3_COMPG(PA, ZA, 2 * g);
    K3_LOADG(PA, ZA, 2 * g + 2);
    K3_COMPG(PB, ZB, 2 * g + 1);
  }
  K3_COMPG(PA, ZA, 24);
  {
    int s = wv * 2;
    int idx = ((ck * 8 + b) * 16 + s) * 512 + d;   // [ck][b][s][d] — coalesced
    *(float4*)&ws[OFF_CHUNK + idx * 4] = make_float4(cp0, h0, S10, S20);
    idx += 512;
    *(float4*)&ws[OFF_CHUNK + idx * 4] = make_float4(cp1, h1, S11, S21);
  }
  if (wv == 0) ws[OFF_ACCDC + (ck * 8 + b) * 512 + d] = xacc;
}

// ================= K4: combine chunks + s-reduce -> ybar =================
// grid (32 dg, 8 b) = 256 blocks; block 256 = 16 d x 16 s.
__global__ __launch_bounds__(256) void k4_scan2(const float* __restrict__ Dvec,
                                                float* __restrict__ ws) {
  const int dg = blockIdx.x;   // 32 groups of 16 d
  const int b  = blockIdx.y;
  const int tid = threadIdx.x;
  const int dl = tid & 15, s = tid >> 4;
  const int d = dg * 16 + dl;
  const int lane = tid & 63, wv = tid >> 6;
  float h = 0.f, y = 0.f;
#pragma unroll
  for (int k = 0; k < 8; ++k) {
    const float4 f = *(const float4*)&ws[OFF_CHUNK + (((k * 8 + b) * 16 + s) * 512 + d) * 4];
    y = fmaf(f.w, h, y + f.z);   // S1 + S2*h_in
    h = fmaf(f.x, h, f.y);       // P*h_in + q
  }
  // reduce over the 4 s-values within each wave (lane bits 4,5)
  y += __shfl_xor(y, 16);
  y += __shfl_xor(y, 32);
  __shared__ float ys[4][16];
  if (lane < 16) ys[wv][dl] = y;
  __syncthreads();
  if (tid < 16) {
    float yt = ys[0][tid] + ys[1][tid] + ys[2][tid] + ys[3][tid];
    float acc = 0.f;
#pragma unroll
    for (int k = 0; k < 8; ++k) acc += ws[OFF_ACCDC + (k * 8 + b) * 512 + dg * 16 + tid];
    int dd = dg * 16 + tid;
    ws[OFF_YBAR + b * 512 + dd] = yt + Dvec[dd] * acc;
  }
}

// ================= K5: out = ybar @ W2s.T + fc_b =================
__global__ __launch_bounds__(64) void k5_out(const float* __restrict__ fc_b,
                                             const float* __restrict__ ws,
                                             float* __restrict__ out) {
  const int b = blockIdx.x;
  const int n = threadIdx.x;
  if (n >= 35) return;
  const float* yb = ws + OFF_YBAR + b * 512;
  const float* w  = ws + OFF_W2S + n * 512;
  float sum = 0.f;
#pragma unroll 8
  for (int k = 0; k < 512; ++k) sum = fmaf(yb[k], w[k], sum);
  out[b * 35 + n] = sum + fc_b[n];
}

extern "C" void kernel_launch(void* const* d_in, const int* in_sizes, int n_in,
                              void* d_out, int out_size, void* d_ws, size_t ws_size,
                              hipStream_t stream) {
  const float* x          = (const float*)d_in[0];
  const float* proj_w     = (const float*)d_in[1];
  const float* proj_b     = (const float*)d_in[2];
  const float* in_proj_w  = (const float*)d_in[3];
  const float* conv_w     = (const float*)d_in[4];
  const float* conv_b     = (const float*)d_in[5];
  const float* x_proj_w   = (const float*)d_in[6];
  const float* dt_proj_w  = (const float*)d_in[7];
  const float* dt_proj_b  = (const float*)d_in[8];
  const float* A_log      = (const float*)d_in[9];
  const float* Dvec       = (const float*)d_in[10];
  const float* out_proj_w = (const float*)d_in[11];
  const float* fc_w       = (const float*)d_in[12];
  const float* fc_b       = (const float*)d_in[13];
  float* ws  = (float*)d_ws;
  float* out = (float*)d_out;
  if (ws_size < (size_t)WS_FLOATS * sizeof(float)) return;  // need ~76 MB scratch

  prep_w1t  <<<dim3(16, 5),    256, 0, stream>>>(proj_w, in_proj_w, ws);
  prep_small<<<106,            256, 0, stream>>>(proj_b, in_proj_w, fc_w, out_proj_w, A_log, ws);
  k1_xz     <<<dim3(16, 17, 8),256, 0, stream>>>(x, conv_w, conv_b, ws);
  k2b_dbc   <<<dim3(500, 2),   256, 0, stream>>>(x_proj_w, ws);
  k2c_pack  <<<dim3(125, 8),   256, 0, stream>>>(dt_proj_w, dt_proj_b, ws);
  k3_scan1  <<<dim3(8, 8, 8),  512, 0, stream>>>(ws);
  k4_scan2  <<<dim3(32, 8),    256, 0, stream>>>(Dvec, ws);
  k5_out    <<<8,              64,  0, stream>>>(fc_b, ws, out);
}